// Round 10
// baseline (36.504 us; speedup 1.0000x reference)
//
#include <hip/hip_runtime.h>
#include <math.h>

typedef float v2f __attribute__((ext_vector_type(2)));

constexpr int NW = 14;
constexpr int DIM = 1 << NW;      // 16384
constexpr int BATCH = 256;
constexpr int NT = 512;           // 8 waves; each thread owns 32 amps, one v2f (re,im) each

// Bank swizzle on float2 (8B) index: fold bits 4..13 into low-4 bank-pair bits.
// XOR-linear; verified: every pass's 6 lane bits map onto {b0,b1,b2,b3} with
// rank 4 => 4 lanes/bank-pair (minimum) => conflict-free ds_*_b64.
__device__ __host__ constexpr int swz2(int i) {
    return i ^ ((i >> 4) & 15)              // i4..i7  -> b0..b3
             ^ (((i >> 8) & 7) << 1)        // i8..i10 -> b1..b3
             ^ ((i >> 11) & 1)              // i11     -> b0
             ^ (((i >> 12) & 3) << 1);      // i12,i13 -> b1,b2
}

// ---------------------------------------------------------------------------
// Packed fp32 primitives (VOP3P, op_sel verified R7/R8).
// P = (c,s): op_sel broadcasts P.lo or P.hi to both halves.
__device__ __forceinline__ v2f pkmul_lo(v2f P, v2f B) {   // P.lo * B
    v2f d; asm("v_pk_mul_f32 %0, %1, %2 op_sel:[0,0] op_sel_hi:[0,1]"
               : "=v"(d) : "v"(P), "v"(B)); return d;
}
__device__ __forceinline__ v2f pkfma_hi(v2f P, v2f B, v2f C) {   // P.hi*B + C
    v2f d; asm("v_pk_fma_f32 %0, %1, %2, %3 op_sel:[1,0,0] op_sel_hi:[1,1,1]"
               : "=v"(d) : "v"(P), "v"(B), "v"(C)); return d;
}
__device__ __forceinline__ v2f pkfmn_hi(v2f P, v2f B, v2f C) {   // -(P.hi)*B + C
    v2f d; asm("v_pk_fma_f32 %0, %1, %2, %3 op_sel:[1,0,0] op_sel_hi:[1,1,1] neg_lo:[1,0,0] neg_hi:[1,0,0]"
               : "=v"(d) : "v"(P), "v"(B), "v"(C)); return d;
}
// cfma_p(P,B,C) = (P.hi,P.hi) * (B.i, -B.r) + C    [complex  -i*s*B + C  form]
__device__ __forceinline__ v2f cfma_p(v2f P, v2f B, v2f C) {
    v2f d; asm("v_pk_fma_f32 %0, %1, %2, %3 op_sel:[1,1,0] op_sel_hi:[1,0,1] neg_hi:[0,1,0]"
               : "=v"(d) : "v"(P), "v"(B), "v"(C)); return d;
}
// cfma_m(P,B,C) = (P.hi,P.hi) * (-B.i, B.r) + C    [complex  +i*s*B + C  form]
__device__ __forceinline__ v2f cfma_m(v2f P, v2f B, v2f C) {
    v2f d; asm("v_pk_fma_f32 %0, %1, %2, %3 op_sel:[1,1,0] op_sel_hi:[1,0,1] neg_lo:[0,1,0]"
               : "=v"(d) : "v"(P), "v"(B), "v"(C)); return d;
}

// ---------------------------------------------------------------------------
// Fused RY/RZ/CNOT/RX gate on local bits JW (wire) and JT (target) of the
// 32-amp (5-bit) register block. Each amp = one v2f (re,im). 24 pk ops/quad.
template<int JW, int JT>
__device__ __forceinline__ void gate_u(v2f (&a)[32], v2f Y, v2f Z, v2f X)
{
    constexpr int BW = 1 << JW, BT = 1 << JT;
    #pragma unroll
    for (int m = 0; m < 8; ++m) {
        int l00 = 0, mm = m;
        #pragma unroll
        for (int j = 0; j < 5; ++j)
            if (j != JW && j != JT) { l00 |= (mm & 1) << j; mm >>= 1; }
        const int iA = l00, iB = l00 | BW, iC = l00 | BT, iD = l00 | BW | BT;

        v2f a00 = a[iA], a10 = a[iB], a01 = a[iC], a11 = a[iD];

        // RY (real) on wire bit
        v2f v0 = pkfmn_hi(Y, a10, pkmul_lo(Y, a00));   // cy*a00 - sy*a10
        v2f v1 = pkfma_hi(Y, a00, pkmul_lo(Y, a10));   // sy*a00 + cy*a10
        v2f u0 = pkfmn_hi(Y, a11, pkmul_lo(Y, a01));
        v2f u1 = pkfma_hi(Y, a01, pkmul_lo(Y, a11));

        // RZ: w=0 rows *= (c1 - i s1); w=1 rows *= (c1 + i s1)
        v2f b00 = cfma_p(Z, v0, pkmul_lo(Z, v0));
        v2f b10 = cfma_m(Z, v1, pkmul_lo(Z, v1));
        v2f b01 = cfma_p(Z, u0, pkmul_lo(Z, u0));
        v2f b11 = cfma_m(Z, u1, pkmul_lo(Z, u1));

        // CNOT(w->t) then RX(w):  o = cx*b  - i sx*b'   (cross pairs)
        a[iA] = cfma_p(X, b11, pkmul_lo(X, b00));  // o00 = cx*b00 - i sx*b11
        a[iB] = cfma_p(X, b00, pkmul_lo(X, b11));  // o10 = -i sx*b00 + cx*b11
        a[iC] = cfma_p(X, b10, pkmul_lo(X, b01));  // o01 = cx*b01 - i sx*b10
        a[iD] = cfma_p(X, b01, pkmul_lo(X, b10));  // o11 = -i sx*b01 + cx*b10
    }
}

// ---------------------------------------------------------------------------
// Scatter thread id t (9 bits) into the 9 bit-positions NOT in {P0..P4}.
template<int P0, int P1, int P2, int P3, int P4>
__device__ __forceinline__ int base_of(int t)
{
    int base = 0, j = 0;
    #pragma unroll
    for (int p = 0; p < NW; ++p) {
        if (p != P0 && p != P1 && p != P2 && p != P3 && p != P4) {
            base |= ((t >> j) & 1) << p;
            ++j;
        }
    }
    return base;
}

template<int P0, int P1, int P2, int P3, int P4>
__device__ __forceinline__ int off_of(int l)
{
    return ((l & 1) << P0) | (((l >> 1) & 1) << P1) | (((l >> 2) & 1) << P2) |
           (((l >> 3) & 1) << P3) | (((l >> 4) & 1) << P4);
}

// LDS round trips: one ds_*_b64 per amp, zero pack movs.
template<int P0, int P1, int P2, int P3, int P4>
__device__ __forceinline__ void lds_load(const float2* cs, v2f (&a)[32], int sb)
{
    #pragma unroll
    for (int l = 0; l < 32; ++l) {
        const int addr = sb ^ swz2(off_of<P0, P1, P2, P3, P4>(l));
        a[l] = *(const v2f*)(cs + addr);
    }
}

template<int P0, int P1, int P2, int P3, int P4>
__device__ __forceinline__ void lds_store(float2* cs, const v2f (&a)[32], int sb)
{
    #pragma unroll
    for (int l = 0; l < 32; ++l) {
        const int addr = sb ^ swz2(off_of<P0, P1, P2, P3, P4>(l));
        *(v2f*)(cs + addr) = a[l];
    }
}

__global__ __launch_bounds__(NT, 1) void qsim(const float* __restrict__ state,
                                              const float* __restrict__ params,
                                              const float* __restrict__ head_w,
                                              const float* __restrict__ head_b,
                                              float* __restrict__ out)
{
    __shared__ float2 cs[DIM];          // 128 KiB, (re,im) interleaved
    __shared__ float2 csv[NW * 3 * 2];  // (cos,sin) of half-angles, 84 gates
    __shared__ float partial[NT / 64];

    const int t = threadIdx.x;
    const int b = blockIdx.x;

    v2f a[32];

    // Pass A layout: locals at P=<10,11,12,13,9>, thread bits at 0..8.
    // HBM load (real input, im=0): for fixed l, lanes read consecutive floats.
    const float* __restrict__ sp = state + (size_t)b * DIM;
    #pragma unroll
    for (int l = 0; l < 32; ++l) {
        a[l] = v2f{sp[t | off_of<10, 11, 12, 13, 9>(l)], 0.0f};
    }

    if (t < NW * 3 * 2) {
        float sv, cv;
        sincosf(params[t] * 0.5f, &sv, &cv);
        csv[t] = make_float2(cv, sv);
    }
    __syncthreads();

#define GU(JW, JT, G) do {                                              \
        v2f Y = *(const v2f*)&csv[(G) * 3 + 0];                         \
        v2f Z = *(const v2f*)&csv[(G) * 3 + 1];                         \
        v2f X = *(const v2f*)&csv[(G) * 3 + 2];                         \
        gate_u<JW, JT>(a, Y, Z, X);                                     \
    } while (0)

    // Every pass: 4 gates on local pairs (3,2),(2,1),(1,0),(0,4).

    // Pass A: L1 wires 0-3, window P=<10,11,12,13,9>, gates 0..3
    GU(3, 2, 0); GU(2, 1, 1); GU(1, 0, 2); GU(0, 4, 3);
    lds_store<10, 11, 12, 13, 9>(cs, a, swz2(base_of<10, 11, 12, 13, 9>(t)));
    __syncthreads();

    // Pass B: L1 wires 4-7, P=<6,7,8,9,5>, gates 4..7
    {
        const int sb = swz2(base_of<6, 7, 8, 9, 5>(t));
        lds_load<6, 7, 8, 9, 5>(cs, a, sb);
        GU(3, 2, 4); GU(2, 1, 5); GU(1, 0, 6); GU(0, 4, 7);
        lds_store<6, 7, 8, 9, 5>(cs, a, sb);
    }
    __syncthreads();

    // Pass C: L1 wires 8-11, P=<2,3,4,5,1>, gates 8..11
    {
        const int sb = swz2(base_of<2, 3, 4, 5, 1>(t));
        lds_load<2, 3, 4, 5, 1>(cs, a, sb);
        GU(3, 2, 8); GU(2, 1, 9); GU(1, 0, 10); GU(0, 4, 11);
        lds_store<2, 3, 4, 5, 1>(cs, a, sb);
    }
    __syncthreads();

    // Pass D: L1 wires 12,13 + L2 wires 0,1, P=<12,13,0,1,11>, gates 12..15
    {
        const int sb = swz2(base_of<12, 13, 0, 1, 11>(t));
        lds_load<12, 13, 0, 1, 11>(cs, a, sb);
        GU(3, 2, 12); GU(2, 1, 13); GU(1, 0, 14); GU(0, 4, 15);
        lds_store<12, 13, 0, 1, 11>(cs, a, sb);
    }
    __syncthreads();

    // Pass E: L2 wires 2-5, P=<8,9,10,11,7>, gates 16..19
    {
        const int sb = swz2(base_of<8, 9, 10, 11, 7>(t));
        lds_load<8, 9, 10, 11, 7>(cs, a, sb);
        GU(3, 2, 16); GU(2, 1, 17); GU(1, 0, 18); GU(0, 4, 19);
        lds_store<8, 9, 10, 11, 7>(cs, a, sb);
    }
    __syncthreads();

    // Pass F: L2 wires 6-9, P=<4,5,6,7,3>, gates 20..23
    {
        const int sb = swz2(base_of<4, 5, 6, 7, 3>(t));
        lds_load<4, 5, 6, 7, 3>(cs, a, sb);
        GU(3, 2, 20); GU(2, 1, 21); GU(1, 0, 22); GU(0, 4, 23);
        lds_store<4, 5, 6, 7, 3>(cs, a, sb);
    }
    __syncthreads();

    // Pass G: L2 wires 10-13, P=<0,1,2,3,13>, gates 24..27; epilogue from regs.
    {
        const int sb = swz2(base_of<0, 1, 2, 3, 13>(t));
        lds_load<0, 1, 2, 3, 13>(cs, a, sb);
        GU(3, 2, 24); GU(2, 1, 25); GU(1, 0, 26); GU(0, 4, 27);
    }

    // Epilogue: out[b] = sum_i |amp_i|^2 * g(i) + head_b.
    // Pass-G roles: l0->bit0(wire13), l1->bit1(w12), l2->bit2(w11), l3->bit3(w10),
    // l4->bit13(w0); thread bits t_j -> bit 4+j -> wire 9-j.
    float hw[NW];
    #pragma unroll
    for (int w = 0; w < NW; ++w) hw[w] = head_w[w];

    float gbase = 0.0f;
    #pragma unroll
    for (int j = 0; j < 9; ++j) {
        float h = hw[9 - j];
        gbase += ((t >> j) & 1) ? -h : h;
    }

    float acc = 0.0f;
    #pragma unroll
    for (int l = 0; l < 32; ++l) {
        float g = gbase;
        g += (l & 1)  ? -hw[13] : hw[13];
        g += (l & 2)  ? -hw[12] : hw[12];
        g += (l & 4)  ? -hw[11] : hw[11];
        g += (l & 8)  ? -hw[10] : hw[10];
        g += (l & 16) ? -hw[0]  : hw[0];
        acc += (a[l].x * a[l].x + a[l].y * a[l].y) * g;
    }

    #pragma unroll
    for (int off = 32; off > 0; off >>= 1) acc += __shfl_down(acc, off);
    if ((t & 63) == 0) partial[t >> 6] = acc;
    __syncthreads();
    if (t == 0) {
        float tot = 0.0f;
        #pragma unroll
        for (int k = 0; k < NT / 64; ++k) tot += partial[k];
        out[b] = tot + head_b[0];
    }
#undef GU
}

extern "C" void kernel_launch(void* const* d_in, const int* in_sizes, int n_in,
                              void* d_out, int out_size, void* d_ws, size_t ws_size,
                              hipStream_t stream) {
    const float* state  = (const float*)d_in[0];
    const float* params = (const float*)d_in[1];
    const float* head_w = (const float*)d_in[2];
    const float* head_b = (const float*)d_in[3];
    float* outp = (float*)d_out;
    qsim<<<BATCH, NT, 0, stream>>>(state, params, head_w, head_b, outp);
}